// Round 6
// baseline (503.326 us; speedup 1.0000x reference)
//
#include <hip/hip_runtime.h>
#include <hip/hip_bf16.h>
#include <stdint.h>

// Problem dims
#define BATCH 256
#define SEQ   512
#define INDIM 64
#define H     128
#define RB    4               // batch rows per block (valid C-rows at quad*4, r=0)
#define NTILE (BATCH / RB)    // 64 batch tiles per layer
#define CH    16              // pipeline handoff chunk (steps)
#define NCH   (SEQ / CH)

using short8  = __attribute__((ext_vector_type(8))) short;  // 8 bf16 MFMA A/B frag
using float4v = __attribute__((ext_vector_type(4))) float;  // MFMA C/D frag

#define LOG2E 1.4426950408889634f

__device__ __forceinline__ unsigned short f2bf(float f) {
    union { float f; uint32_t u; } v; v.f = f;
    uint32_t u = v.u;
    return (unsigned short)((u + 0x7FFFu + ((u >> 16) & 1u)) >> 16); // RNE
}

__device__ __forceinline__ float fast_exp2(float x) {
#if __has_builtin(__builtin_amdgcn_exp2f)
    return __builtin_amdgcn_exp2f(x);
#else
    return __expf(x * 0.6931471805599453f);
#endif
}
__device__ __forceinline__ float fast_rcp(float x) {
#if __has_builtin(__builtin_amdgcn_rcpf)
    return __builtin_amdgcn_rcpf(x);
#else
    return 1.f / x;
#endif
}

// In-step barrier: LDS ordering only (lgkmcnt). Global prefetch loads and
// producer h-stores stay in flight across it. Full __syncthreads (vmcnt
// drain) only at producer chunk boundaries.
__device__ __forceinline__ void light_barrier() {
    asm volatile("s_waitcnt lgkmcnt(0)\n\ts_barrier" ::: "memory");
}

// ---------------- x fp32 -> bf16 convert (+ flag zeroing) ----------------
__global__ void conv_x_kernel(const float* __restrict__ x,
                              unsigned short* __restrict__ xb, int n4,
                              int* __restrict__ flags) {
    int i = blockIdx.x * blockDim.x + threadIdx.x;
    if (blockIdx.x == 0 && threadIdx.x < NTILE) flags[threadIdx.x] = 0;
    if (i >= n4) return;
    float4 f = ((const float4*)x)[i];
    ushort4 o;
    o.x = f2bf(f.x); o.y = f2bf(f.y); o.z = f2bf(f.z); o.w = f2bf(f.w);
    ((ushort4*)xb)[i] = o;
}

// ---------------- fused 2-layer pipelined LSTM + head ----------------
// 128 blocks x 512 threads (R3/R5 skeleton = the 407-410us verified
// structure). Blocks 0..63: layer0 (producer), 64..127: layer1 (consumer),
// paired on batch tile bt via chunked flag handoff through global h0sq.
//
// Established constraints:
//  - R2: register-persistent weights force 2 waves/SIMD; higher occupancy
//    spills catastrophically. Only lever: per-step serial critical path.
//  - R3 (verified): depth-4 -> depth-2 h-MFMA chains: -8%. Per-level MFMA
//    dependent latency ~33cy (measured via R0->R3 delta).
//  - R4 (failed): dist-1 consumer x reload stalls on cross-CU h0sq reads.
//    Consumer prefetch distance MUST stay 2 steps.
//  - R5 (neutral): acc-init movs were already hidden; seeds kept (harmless).
//  - Depth-1 h-chains (4 accs) rejected: +32 in-flight regs -> ~260 peak,
//    past the R2/R4 spill cliff, for only ~17cy.
//
// R6 changes vs R5 (two mechanisms):
//  (1) exp2-domain weight pre-scaling: Wih/Whh/bias for gates i,f,o scaled
//      by -log2e and gate g by +2*log2e at fragment-load time; cell state
//      kept as c~ = 2*log2e*c. sigmoid = rcp(1+exp2(g')), tanh(g) =
//      fmaf(-2,rcp(1+exp2(g')),1), h = fmaf(-2so, rcp(1+exp2(c~)), so).
//      Activation critical chain 14 -> 11 dependent ops (~-36cy/step).
//  (2) consumer chunk trim (safe subset of R4): 2-chunk flag lag, per-wave
//      poll (no thread0-spin+syncthreads), fill once at ch==0, prefetch
//      crosses chunk boundaries; dist-2 KEPT. Deletes per-chunk blocking
//      refill + 2 sync constructs (~-40cy/step amortized).
// R5 lesson (still enforced): every per-thread register array is indexed
// ONLY with compile-time constants; x double buffer statically named.
template<int KIN, bool IS_PROD>
__device__ __forceinline__ void lstm_body(
    const unsigned short* __restrict__ xin,  // [BATCH][SEQ][KIN] bf16
    const float* __restrict__ Wih,           // [4H][KIN]
    const float* __restrict__ Whh,           // [4H][H]
    const float* __restrict__ b_ih, const float* __restrict__ b_hh,
    unsigned short* __restrict__ outseq,     // producer: [BATCH][SEQ][H] bf16
    const float* __restrict__ W1, const float* __restrict__ b1,
    const float* __restrict__ W2, const float* __restrict__ b2,
    float* __restrict__ out,                 // consumer: [BATCH][3]
    int* flag, int bt)
{
    constexpr int KT  = KIN / 32;
    constexpr int PAD = 132;                 // 66 dwords == 2 mod 32 -> 2-way (free) aliasing
    const int lane = threadIdx.x & 63;
    const int quad = lane >> 4;
    const int l16  = lane & 15;
    const int b0   = bt * RB;
    const int cell = (threadIdx.x >> 6) * 16 + l16;
    const int arow = l16 & 12;               // LDS h row this lane reads (4-lane broadcast)
    const int xrow = b0 + (l16 >> 2);        // batch row this lane loads (duplicated 4x)

    __shared__ short hbuf[2][16][PAD];
    __shared__ float hl[RB][128];            // fp32 h_last (consumer head input)
    __shared__ float mid[RB][65];
    for (int i = threadIdx.x; i < 2 * 16 * PAD; i += 512) ((short*)hbuf)[i] = 0;

    // ---- weight fragments (loaded once, fp32->bf16, persist in registers).
    //      Pre-scaled into the exp2 domain: gates i,f,o by -log2e, gate g by
    //      +2*log2e (R6 change 1).
    short8 whh_f[4][4];
    short8 wih_f[4][KT];
    float  bias[4];
#pragma unroll
    for (int tT = 0; tT < 4; tT++) {
        const float sc = (tT == 2) ? (2.0f * LOG2E) : (-LOG2E);
        const int n = tT * 128 + cell;
#pragma unroll
        for (int kt = 0; kt < 4; kt++) {
            const float* p = Whh + (size_t)n * H + kt * 32 + quad * 8;
            float4 f0 = *(const float4*)p;
            float4 f1 = *(const float4*)(p + 4);
            short8 s;
            s[0]=f2bf(f0.x*sc); s[1]=f2bf(f0.y*sc); s[2]=f2bf(f0.z*sc); s[3]=f2bf(f0.w*sc);
            s[4]=f2bf(f1.x*sc); s[5]=f2bf(f1.y*sc); s[6]=f2bf(f1.z*sc); s[7]=f2bf(f1.w*sc);
            whh_f[tT][kt] = s;
        }
#pragma unroll
        for (int kt = 0; kt < KT; kt++) {
            const float* p = Wih + (size_t)n * KIN + kt * 32 + quad * 8;
            float4 f0 = *(const float4*)p;
            float4 f1 = *(const float4*)(p + 4);
            short8 s;
            s[0]=f2bf(f0.x*sc); s[1]=f2bf(f0.y*sc); s[2]=f2bf(f0.z*sc); s[3]=f2bf(f0.w*sc);
            s[4]=f2bf(f1.x*sc); s[5]=f2bf(f1.y*sc); s[6]=f2bf(f1.z*sc); s[7]=f2bf(f1.w*sc);
            wih_f[tT][kt] = s;
        }
        bias[tT] = (b_ih[n] + b_hh[n]) * sc;
    }

    // ---- persistent seed registers (R5) ----
    float4v bias4[4], zero4;
#pragma unroll
    for (int tT = 0; tT < 4; tT++)
        bias4[tT] = (float4v){bias[tT], bias[tT], bias[tT], bias[tT]};
    zero4 = (float4v){0.f, 0.f, 0.f, 0.f};
    asm volatile("" : "+v"(bias4[0]), "+v"(bias4[1]), "+v"(bias4[2]),
                      "+v"(bias4[3]), "+v"(zero4));

    float c0 = 0.f;                          // c-tilde state: 2*log2e * c

    const unsigned short* xp = xin + ((size_t)xrow * SEQ) * KIN + quad * 8;
    unsigned short* op = nullptr;
    if (IS_PROD)
        op = outseq + ((size_t)(b0 + quad) * SEQ) * H + cell;

    short8 xf0[KT], xf1[KT];                 // statically-named x double buffer
    __syncthreads();                         // hbuf zero-init visible

    // One step. Consumes xf (= x(t)); reloads xf = x(t+2) right after the
    // x-MFMAs (dist-2: covers cross-CU h0sq / LLC latency). Gate math:
    //   accA = bias' + x0 + x1 + h0 + h1   (seeded from bias4)
    //   accB = [x2 + x3 +] h2 + h3         (seeded from zero4)
    //   g' = accA[0] + accB[0]             (already exp2-domain scaled)
    auto step = [&](int t, int CUR, short8 (&xf)[KT],
                    bool doPre) __attribute__((always_inline)) {
        short8 ha[4];
#pragma unroll
        for (int kt = 0; kt < 4; kt++)
            ha[kt] = *(const short8*)&hbuf[CUR][arow][kt * 32 + quad * 8];

        float4v accA[4], accB[4];            // in-step only, seeded via first MFMA
        // x-projection from prefetched regs (fills the ds_read latency window)
#pragma unroll
        for (int tT = 0; tT < 4; tT++)
            accA[tT] = __builtin_amdgcn_mfma_f32_16x16x32_bf16(xf[0], wih_f[tT][0], bias4[tT], 0, 0, 0);
#pragma unroll
        for (int tT = 0; tT < 4; tT++)
            accA[tT] = __builtin_amdgcn_mfma_f32_16x16x32_bf16(xf[1], wih_f[tT][1], accA[tT], 0, 0, 0);
        if constexpr (KT == 4) {
#pragma unroll
            for (int tT = 0; tT < 4; tT++)
                accB[tT] = __builtin_amdgcn_mfma_f32_16x16x32_bf16(xf[2], wih_f[tT][2], zero4, 0, 0, 0);
#pragma unroll
            for (int tT = 0; tT < 4; tT++)
                accB[tT] = __builtin_amdgcn_mfma_f32_16x16x32_bf16(xf[3], wih_f[tT][3], accB[tT], 0, 0, 0);
        }
        if (doPre) {                         // reload xf = x(t+2) (WAR after use)
            const unsigned short* p = xp + (size_t)(t + 2) * KIN;
#pragma unroll
            for (int kt = 0; kt < KT; kt++) xf[kt] = *(const short8*)(p + kt * 32);
        }
        // recurrent projection: two parallel depth-2 chains
#pragma unroll
        for (int tT = 0; tT < 4; tT++)
            accA[tT] = __builtin_amdgcn_mfma_f32_16x16x32_bf16(ha[0], whh_f[tT][0], accA[tT], 0, 0, 0);
        if constexpr (KT == 4) {
#pragma unroll
            for (int tT = 0; tT < 4; tT++)
                accB[tT] = __builtin_amdgcn_mfma_f32_16x16x32_bf16(ha[2], whh_f[tT][2], accB[tT], 0, 0, 0);
        } else {
#pragma unroll
            for (int tT = 0; tT < 4; tT++)
                accB[tT] = __builtin_amdgcn_mfma_f32_16x16x32_bf16(ha[2], whh_f[tT][2], zero4, 0, 0, 0);
        }
#pragma unroll
        for (int tT = 0; tT < 4; tT++)
            accA[tT] = __builtin_amdgcn_mfma_f32_16x16x32_bf16(ha[1], whh_f[tT][1], accA[tT], 0, 0, 0);
#pragma unroll
        for (int tT = 0; tT < 4; tT++)
            accB[tT] = __builtin_amdgcn_mfma_f32_16x16x32_bf16(ha[3], whh_f[tT][3], accB[tT], 0, 0, 0);

        float g0 = accA[0][0] + accB[0][0];  // -L * i-preact
        float g1 = accA[1][0] + accB[1][0];  // -L * f-preact
        float g2 = accA[2][0] + accB[2][0];  // 2L * g-preact
        float g3 = accA[3][0] + accB[3][0];  // -L * o-preact

        // exp2-domain activations (11 dependent ops g->h)
        float si = fast_rcp(1.f + fast_exp2(g0));                 // sigmoid(i)
        float sf = fast_rcp(1.f + fast_exp2(g1));                 // sigmoid(f)
        float tg = fmaf(-2.f, fast_rcp(1.f + fast_exp2(g2)), 1.f);// tanh(g)
        float so = fast_rcp(1.f + fast_exp2(g3));                 // sigmoid(o)
        float si2 = si * (2.0f * LOG2E);
        c0 = fmaf(sf, c0, si2 * tg);          // c~ = 2L*c
        float r  = fast_rcp(1.f + fast_exp2(c0));
        float nso2 = -2.f * so;
        float h  = fmaf(nso2, r, so);         // so * tanh(c)
        uint32_t hp;                          // single-instr RNE f32->bf16
        asm("v_cvt_pk_bf16_f32 %0, %1, %2" : "=v"(hp) : "v"(h), "v"(h));
        hbuf[CUR ^ 1][quad * 4][cell] = (short)(hp & 0xffffu);
        if (IS_PROD) {
            *op = (unsigned short)(hp & 0xffffu);  // fire-and-forget; drained at chunk end
            op += H;
        } else if (t == SEQ - 1) {
            hl[quad][cell] = h;
        }
        light_barrier();                     // LDS-only: loads/stores stay in flight
    };

    for (int ch = 0; ch < NCH; ch++) {
        const int t0 = ch * CH;
        if (!IS_PROD) {
            // per-wave poll, 2-chunk lag: chunks 0..ch+1 guaranteed written
            // before chunk ch starts, so in-step dist-2 prefetch may cross
            // into chunk ch+1 freely (R6 change 2).
            const int want = (ch + 2 < NCH) ? (ch + 2) : NCH;
            while (__hip_atomic_load(flag, __ATOMIC_RELAXED, __HIP_MEMORY_SCOPE_AGENT) < want)
                __builtin_amdgcn_s_sleep(2);
            (void)__hip_atomic_load(flag, __ATOMIC_ACQUIRE, __HIP_MEMORY_SCOPE_AGENT);
        }
        if (ch == 0) {                       // one-time fill; pipeline self-sustains after
            const unsigned short* p0 = xp;
#pragma unroll
            for (int kt = 0; kt < KT; kt++) {
                xf0[kt] = *(const short8*)(p0 + kt * 32);
                xf1[kt] = *(const short8*)(p0 + KIN + kt * 32);
            }
        }

#pragma unroll 1
        for (int i = 0; i < CH; i += 2) {
            const int t = t0 + i;
            step(t,     0, xf0, t + 2 < SEQ);  // even -> reads hbuf[0], writes hbuf[1]
            step(t + 1, 1, xf1, t + 3 < SEQ);  // odd  -> reads hbuf[1], writes hbuf[0]
        }
        if constexpr (IS_PROD) {
            __syncthreads();                 // vmcnt drain (h0sq stores) for release
            if (threadIdx.x == 0)
                __hip_atomic_fetch_add(flag, 1, __ATOMIC_RELEASE, __HIP_MEMORY_SCOPE_AGENT);
        }
    }

    if (!IS_PROD) {
        // ---- MLP head for this block's RB rows (hl visible via last light_barrier)
        if (threadIdx.x < RB * 64) {
            const int row = threadIdx.x >> 6, j = threadIdx.x & 63;
            float s = b1[j];
            const float* wr = W1 + (size_t)j * 128;
#pragma unroll 8
            for (int k = 0; k < 128; k++) s = fmaf(hl[row][k], wr[k], s);
            mid[row][j] = fmaxf(s, 0.f);
        }
        __syncthreads();
        if (threadIdx.x < RB * 3) {
            const int row = threadIdx.x / 3, k = threadIdx.x - row * 3;
            float o = b2[k];
            const float* wr = W2 + (size_t)k * 64;
#pragma unroll 8
            for (int j = 0; j < 64; j++) o = fmaf(mid[row][j], wr[j], o);
            out[(size_t)(b0 + row) * 3 + k] = o;
        }
    }
}

__global__ __launch_bounds__(512, 2)
void lstm_fused_kernel(const unsigned short* __restrict__ xb,
                       const float* __restrict__ Wih0, const float* __restrict__ Whh0,
                       const float* __restrict__ bih0, const float* __restrict__ bhh0,
                       const float* __restrict__ Wih1, const float* __restrict__ Whh1,
                       const float* __restrict__ bih1, const float* __restrict__ bhh1,
                       unsigned short* __restrict__ h0sq,
                       const float* __restrict__ W1, const float* __restrict__ b1,
                       const float* __restrict__ W2, const float* __restrict__ b2,
                       float* __restrict__ out,
                       int* __restrict__ flags)
{
    const int bt = blockIdx.x & (NTILE - 1);
    if (blockIdx.x < NTILE)
        lstm_body<64,  true >(xb,   Wih0, Whh0, bih0, bhh0, h0sq,
                              W1, b1, W2, b2, out, flags + bt, bt);
    else
        lstm_body<128, false>(h0sq, Wih1, Whh1, bih1, bhh1, nullptr,
                              W1, b1, W2, b2, out, flags + bt, bt);
}

extern "C" void kernel_launch(void* const* d_in, const int* in_sizes, int n_in,
                              void* d_out, int out_size, void* d_ws, size_t ws_size,
                              hipStream_t stream) {
    const float* x     = (const float*)d_in[0];
    const float* W_ih0 = (const float*)d_in[1];
    const float* W_hh0 = (const float*)d_in[2];
    const float* b_ih0 = (const float*)d_in[3];
    const float* b_hh0 = (const float*)d_in[4];
    const float* W_ih1 = (const float*)d_in[5];
    const float* W_hh1 = (const float*)d_in[6];
    const float* b_ih1 = (const float*)d_in[7];
    const float* b_hh1 = (const float*)d_in[8];
    const float* W1    = (const float*)d_in[9];
    const float* b1    = (const float*)d_in[10];
    const float* W2    = (const float*)d_in[11];
    const float* b2    = (const float*)d_in[12];
    float* out = (float*)d_out;

    // workspace: xb bf16[256*512*64] @0 (16 MB); h0sq bf16[256*512*128] @16 MB (32 MB); flags @48 MB
    char* ws = (char*)d_ws;
    unsigned short* xb    = (unsigned short*)ws;
    unsigned short* h0sq  = (unsigned short*)(ws + 16777216);
    int*            flags = (int*)(ws + 50331648);

    conv_x_kernel<<<8192, 256, 0, stream>>>(x, xb, (BATCH * SEQ * INDIM) / 4, flags);
    lstm_fused_kernel<<<2 * NTILE, 512, 0, stream>>>(xb, W_ih0, W_hh0, b_ih0, b_hh0,
                                                     W_ih1, W_hh1, b_ih1, b_hh1,
                                                     h0sq, W1, b1, W2, b2, out, flags);
}